// Round 3
// baseline (73.536 us; speedup 1.0000x reference)
//
#include <hip/hip_runtime.h>

// SparseLookupTable: out[b,o] = sum_{k<128} lut[inp[b,k], wgt[o,k]]
// B=512, O=1024, K=128, LUT 256x256 fp32.
//
// R3: fp16 LUT in LDS (128 KB); wave-uniform rows (SALU offsets via
// readfirstlane); ALL index reads are ds_read_b128 (rows: broadcast b128 per
// 16-k group; cols: blocked [g][o][4] layout, 16B-aligned, bank-balanced).
// Tile 16b x 128o per 1024-thread block, 2 outputs/thread.

#define BATCH 512
#define OUTF  1024
#define KDIM  128
#define MIDX  256

typedef _Float16 half4v __attribute__((ext_vector_type(4)));

__global__ __launch_bounds__(1024, 1)
void slt_kernel(const int* __restrict__ inp, const int* __restrict__ wgt,
                const float* __restrict__ lut, float* __restrict__ out) {
    // 128 KB LUT + 2 KB rows + 16 KB cols = 146 KB LDS
    __shared__ __attribute__((aligned(16))) _Float16 lut16[MIDX * MIDX];
    __shared__ __attribute__((aligned(16))) unsigned int wrow_pack[16 * 32];       // [b][q]
    __shared__ __attribute__((aligned(16))) unsigned int wcol_pack[8 * 128 * 4];   // [g][o][j]

    const int tid   = threadIdx.x;
    const int otile = blockIdx.x;   // 8 tiles of 128 outputs
    const int btile = blockIdx.y;   // 32 tiles of 16 batch rows

    // ---- stage LUT fp32 -> fp16 (each thread: 16 x float4 -> half4) ----
    const float4* lut4 = (const float4*)lut;
    half4v* l16v = (half4v*)lut16;
    #pragma unroll
    for (int it = 0; it < 16; ++it) {
        int idx = it * 1024 + tid;
        float4 v = lut4[idx];
        half4v h = { (_Float16)v.x, (_Float16)v.y, (_Float16)v.z, (_Float16)v.w };
        l16v[idx] = h;
    }

    // ---- stage input rows, u8-packed: wrow_pack[b*32+q] = inp[b][4q..4q+3] ----
    if (tid < 512) {
        int b = tid >> 5;
        int q = tid & 31;
        const int4 iv = *(const int4*)(inp + ((size_t)(btile * 16 + b)) * KDIM + q * 4);
        wrow_pack[b * 32 + q] = (unsigned int)(iv.x & 255)
                              | ((unsigned int)(iv.y & 255) << 8)
                              | ((unsigned int)(iv.z & 255) << 16)
                              | ((unsigned int)(iv.w & 255) << 24);
    }

    // ---- stage weight cols, u8-packed, blocked: wcol_pack[(q>>2)*512 + o*4 + (q&3)] ----
    {
        int o = tid >> 3;          // 0..127
        int jj = tid & 7;
        const int* wbase = wgt + ((size_t)(otile * 128 + o)) * KDIM;
        #pragma unroll
        for (int i = 0; i < 4; ++i) {
            int q = jj + 8 * i;    // coalesced int4 reads
            const int4 wv = *(const int4*)(wbase + q * 4);
            unsigned int pw = (unsigned int)(wv.x & 255)
                            | ((unsigned int)(wv.y & 255) << 8)
                            | ((unsigned int)(wv.z & 255) << 16)
                            | ((unsigned int)(wv.w & 255) << 24);
            wcol_pack[(q >> 2) * 512 + o * 4 + (q & 3)] = pw;
        }
    }

    __syncthreads();

    const int w    = tid >> 6;  // wave id = b-row within tile
    const int lane = tid & 63;  // o = lane and lane+64

    float a0 = 0.f, a1 = 0.f, b0 = 0.f, b1 = 0.f;

    #pragma unroll 2
    for (int g = 0; g < 8; ++g) {
        // one broadcast b128: rows for 16 k's (wave-uniform)
        uint4 rw = *(const uint4*)&wrow_pack[w * 32 + 4 * g];
        // two b128s: cols for 16 k's, for o=lane and o=lane+64
        uint4 c0 = *(const uint4*)&wcol_pack[g * 512 + lane * 4];
        uint4 c1 = *(const uint4*)&wcol_pack[g * 512 + (lane + 64) * 4];

        unsigned int rws[4] = { rw.x, rw.y, rw.z, rw.w };
        unsigned int w0s[4] = { c0.x, c0.y, c0.z, c0.w };
        unsigned int w1s[4] = { c1.x, c1.y, c1.z, c1.w };

        #pragma unroll
        for (int j = 0; j < 4; ++j) {
            unsigned int rword = (unsigned int)__builtin_amdgcn_readfirstlane((int)rws[j]);
            // scalar row bases (element index into lut16)
            int rb0 = (int)((rword       & 255u) << 8);
            int rb1 = (int)(((rword >> 8) & 255u) << 8);
            int rb2 = (int)(((rword >> 16) & 255u) << 8);
            int rb3 = (int)((rword >> 24) << 8);
            unsigned int u0 = w0s[j], u1 = w1s[j];

            a0 += (float)lut16[rb0 + (int)(u0 & 255u)];
            a1 += (float)lut16[rb0 + (int)(u1 & 255u)];
            b0 += (float)lut16[rb1 + (int)((u0 >> 8) & 255u)];
            b1 += (float)lut16[rb1 + (int)((u1 >> 8) & 255u)];
            a0 += (float)lut16[rb2 + (int)((u0 >> 16) & 255u)];
            a1 += (float)lut16[rb2 + (int)((u1 >> 16) & 255u)];
            b0 += (float)lut16[rb3 + (int)(u0 >> 24)];
            b1 += (float)lut16[rb3 + (int)(u1 >> 24)];
        }
    }

    size_t ob = ((size_t)(btile * 16 + w)) * OUTF + (size_t)(otile * 128) + lane;
    out[ob]      = a0 + b0;
    out[ob + 64] = a1 + b1;
}

extern "C" void kernel_launch(void* const* d_in, const int* in_sizes, int n_in,
                              void* d_out, int out_size, void* d_ws, size_t ws_size,
                              hipStream_t stream) {
    const int*   inp = (const int*)d_in[0];    // (512, 32, 4) int32
    const int*   wgt = (const int*)d_in[1];    // (1024, 32, 4) int32
    const float* lut = (const float*)d_in[2];  // (256, 256) fp32
    float*       out = (float*)d_out;          // (512, 1024) fp32

    dim3 grid(8, 32);   // 256 blocks, ~1 per CU
    dim3 block(1024);
    slt_kernel<<<grid, block, 0, stream>>>(inp, wgt, lut, out);
}